// Round 5
// baseline (631.485 us; speedup 1.0000x reference)
//
#include <hip/hip_runtime.h>

// ---- types ----
typedef __bf16 bf16x8 __attribute__((ext_vector_type(8)));
typedef float  floatx4 __attribute__((ext_vector_type(4)));
typedef float  fvec4  __attribute__((ext_vector_type(4)));
typedef unsigned short ushort4v __attribute__((ext_vector_type(4)));
typedef unsigned short ushort8v __attribute__((ext_vector_type(8)));

__device__ __forceinline__ unsigned short f2bf(float f) {
  unsigned int u = __float_as_uint(f);
  u = u + 0x7FFFu + ((u >> 16) & 1u);   // RNE
  return (unsigned short)(u >> 16);
}

// ws layout (u16-elem offsets unless noted). 8 stages: A1 A2 A3 A4 B1 B2 C1 C2,
// base layers {0,4,8,12,15,19,23,27}, NSUB {4,4,4,3,4,4,4,4}, CS {1,1,1,1,2,1,2,1}.
//  WD2  [29][2 tap][256 n][256 c]        @ 0          (compose B-operand, tap planes)
//  WT2  [29][2 tap][256 i][256 c]        @ 3801088    (compose A-operand, transposed)
//  WT3  [2][3 tap][256 i][256 c]         @ 7602176
//  X0..X27 carriers (pitched bf16)       @ 8388608
//  SW   stage weight blocks (tap planes) @ 12582912   (d1 copied, d2-4 composed)
//  CPA  composed A-layout planes         @ 20971520   (for chained compose)
//  beff fp32 [8][4][256]                 @ byte 62914560
//  tbl  u16 [16384]                      @ elem 32505856 (byte 65011712)
//  Y    fp32 [31][16*256][128]           @ byte 67108864
#define X0_E   8388608
#define X4_E   8945664
#define X8_E   9502720
#define X12_E  10059776
#define X15_E  10616832
#define X19_E  11173888
#define X23_E  11468800
#define X27_E  11763712
#define TBL_E  32505856
#define BEFF_B 62914560
#define Y_B    67108864

__device__ __host__ __forceinline__ constexpr int swo_at(int s) {
  constexpr int SWO_[8] = {12582912,13500416,14417920,15335424,15925248,17498112,18415616,19988480};
  return SWO_[s];
}

// ---- prep0: WD2, X0 (pitch 136), stage d1 plane copies, tbl ----
__global__ __launch_bounds__(256) void prep0_kernel(
    const float* __restrict__ w2, const float* __restrict__ w3,
    const float* __restrict__ x, unsigned short* __restrict__ ws)
{
  const int g = blockIdx.x * 256 + threadIdx.x;     // 0 .. 1327103
  if (g < 950272) {                                  // WD2 de-interleave
    const long f = (long)4 * g;
    fvec4 v = *reinterpret_cast<const fvec4*>(w2 + f);
    const int c = (int)((f >> 1) & 255), n = (int)((f >> 9) & 255), l = (int)(f >> 17);
    unsigned int p0 = (unsigned int)f2bf(v[0]) | ((unsigned int)f2bf(v[2]) << 16);
    unsigned int p1 = (unsigned int)f2bf(v[1]) | ((unsigned int)f2bf(v[3]) << 16);
    *reinterpret_cast<unsigned int*>(ws + (l * 2 + 0) * 65536 + n * 256 + c) = p0;
    *reinterpret_cast<unsigned int*>(ws + (l * 2 + 1) * 65536 + n * 256 + c) = p1;
  } else if (g < 1081344) {                          // X0 bf16, pitch 136
    const int h = g - 950272;
    const int row = h >> 5, col = (h & 31) * 4;
    fvec4 v = *reinterpret_cast<const fvec4*>(x + (long)row * 128 + col);
    ushort4v o;
    o[0] = f2bf(v[0]); o[1] = f2bf(v[1]); o[2] = f2bf(v[2]); o[3] = f2bf(v[3]);
    *reinterpret_cast<ushort4v*>(ws + X0_E + row * 136 + col) = o;
  } else if (g < 1277952) {                          // d1 planes, cs1 stages
    const int h = g - 1081344;
    const int s6 = h >> 15, hh = h & 32767;
    constexpr int SD1[6] = {0,1,2,3,5,7};
    constexpr int LD1[6] = {0,4,8,12,18,25};
    unsigned short* dst = ws + swo_at(SD1[s6]);
    const long f = (long)LD1[s6] * 131072 + 4 * hh;
    fvec4 v = *reinterpret_cast<const fvec4*>(w2 + f);
    const int c = (int)((4 * hh >> 1) & 255), n = (int)((4 * hh) >> 9);
    unsigned int p0 = (unsigned int)f2bf(v[0]) | ((unsigned int)f2bf(v[2]) << 16);
    unsigned int p1 = (unsigned int)f2bf(v[1]) | ((unsigned int)f2bf(v[3]) << 16);
    *reinterpret_cast<unsigned int*>(dst + n * 256 + c) = p0;
    *reinterpret_cast<unsigned int*>(dst + 65536 + n * 256 + c) = p1;
  } else if (g < 1310720) {                          // d1 planes, cs2 stages (w3 tap-major)
    const int h = g - 1277952;
    const int g3 = h >> 14, rest = h & 16383;
    const int n = rest >> 6, i4 = (rest & 63) * 4;
    const float* base = w3 + ((long)(g3 * 256 + n) * 256 + i4) * 3;
    fvec4 v0 = *reinterpret_cast<const fvec4*>(base);
    fvec4 v1 = *reinterpret_cast<const fvec4*>(base + 4);
    fvec4 v2 = *reinterpret_cast<const fvec4*>(base + 8);
    float e[12] = {v0[0],v0[1],v0[2],v0[3],v1[0],v1[1],v1[2],v1[3],v2[0],v2[1],v2[2],v2[3]};
    unsigned short* dst = ws + swo_at(g3 ? 6 : 4);
#pragma unroll
    for (int t = 0; t < 3; ++t) {
      ushort4v o;
      o[0] = f2bf(e[t]); o[1] = f2bf(e[3 + t]); o[2] = f2bf(e[6 + t]); o[3] = f2bf(e[9 + t]);
      *reinterpret_cast<ushort4v*>(dst + t * 65536 + n * 256 + i4) = o;
    }
  } else {                                           // tbl
    const int h = g - 1310720;
    const int r = h >> 7, c = h & 127, d = c - r;
    unsigned short v = 0xFFFFu;
    if (d == 0) v = (unsigned short)(31 * 129 + r);
    else if (d >= 1 && d <= 15) v = (unsigned short)((d - 1) * 129 + r);
    else if (d >= 17 && d <= 31 && (d & 1) == 1 && (r & 1) == 0)
      v = (unsigned short)((15 + ((d - 17) >> 1)) * 129 + (r >> 1));
    else if (d >= 35 && d <= 63 && (d & 3) == 3 && (r & 3) == 0)
      v = (unsigned short)((23 + ((d - 35) >> 2)) * 129 + (r >> 2));
    ws[TBL_E + h] = v;
  }
}

// ---- transposed weight copies (LDS tile transpose; same as validated R4 kernel) ----
__global__ __launch_bounds__(256) void wt_kernel(
    const float* __restrict__ w2, const float* __restrict__ w3,
    unsigned short* __restrict__ ws)
{
  __shared__ unsigned short T[3 * 64 * 65];
  unsigned short* wt2 = ws + 3801088;
  unsigned short* wt3 = ws + 7602176;
  const int bid = blockIdx.x, tid = threadIdx.x;
  if (bid < 464) {
    const int l = bid >> 4, t16 = bid & 15, it = t16 & 3, ct = t16 >> 2;
    const int cc = tid >> 2, q = tid & 3;
    const int c = ct * 64 + cc;
    const long rb = ((long)(l * 256 + c) * 256 + it * 64 + q * 16) * 2;
#pragma unroll
    for (int u2 = 0; u2 < 8; ++u2) {
      fvec4 v = *reinterpret_cast<const fvec4*>(w2 + rb + u2 * 4);
      const int il = q * 16 + u2 * 2;
      T[0 * 4160 + cc * 65 + il]     = f2bf(v[0]);
      T[1 * 4160 + cc * 65 + il]     = f2bf(v[1]);
      T[0 * 4160 + cc * 65 + il + 1] = f2bf(v[2]);
      T[1 * 4160 + cc * 65 + il + 1] = f2bf(v[3]);
    }
    __syncthreads();
    const int b = tid >> 7, rest = tid & 127, i_loc = rest >> 1, half = rest & 1;
    unsigned short* dp = wt2 + ((long)((l * 2 + b) * 256 + it * 64 + i_loc)) * 256
                             + ct * 64 + half * 32;
#pragma unroll
    for (int v8 = 0; v8 < 4; ++v8) {
      ushort8v o;
#pragma unroll
      for (int e = 0; e < 8; ++e) o[e] = T[b * 4160 + (half * 32 + v8 * 8 + e) * 65 + i_loc];
      *reinterpret_cast<ushort8v*>(dp + v8 * 8) = o;
    }
  } else {
    const int u = bid - 464, g = u >> 4, t16 = u & 15, it = t16 & 3, ct = t16 >> 2;
    const int cc = tid >> 2, q = tid & 3;
    const int c = ct * 64 + cc;
    const long rb = ((long)(g * 256 + c) * 256 + it * 64 + q * 16) * 3;
#pragma unroll
    for (int u4 = 0; u4 < 4; ++u4) {
      fvec4 v0 = *reinterpret_cast<const fvec4*>(w3 + rb + u4 * 12);
      fvec4 v1 = *reinterpret_cast<const fvec4*>(w3 + rb + u4 * 12 + 4);
      fvec4 v2 = *reinterpret_cast<const fvec4*>(w3 + rb + u4 * 12 + 8);
      const int il = q * 16 + u4 * 4;
      float e[12] = {v0[0],v0[1],v0[2],v0[3],v1[0],v1[1],v1[2],v1[3],v2[0],v2[1],v2[2],v2[3]};
#pragma unroll
      for (int di = 0; di < 4; ++di)
#pragma unroll
        for (int tp = 0; tp < 3; ++tp)
          T[tp * 4160 + cc * 65 + il + di] = f2bf(e[di * 3 + tp]);
    }
    __syncthreads();
    if (tid < 192) {
      const int tp = tid >> 6, i_loc = tid & 63;
      unsigned short* dp = wt3 + ((long)((g * 3 + tp) * 256 + it * 64 + i_loc)) * 256 + ct * 64;
#pragma unroll
      for (int v8 = 0; v8 < 8; ++v8) {
        ushort8v o;
#pragma unroll
        for (int e2 = 0; e2 < 8; ++e2) o[e2] = T[tp * 4160 + (v8 * 8 + e2) * 65 + i_loc];
        *reinterpret_cast<ushort8v*>(dp + v8 * 8) = o;
      }
    }
  }
}

__device__ __forceinline__ int w2idx(int l) { return l < 15 ? l : (l < 23 ? l - 1 : l - 2); }

// ---- chained bias: beff[s][d] = b_ld + W_ld(row-sum over taps) . beff[s][d-1], fp32 ----
__global__ __launch_bounds__(256) void beff_kernel(
    const float* __restrict__ w2, const float* __restrict__ b2,
    const float* __restrict__ b3, float* __restrict__ beff)
{
  __shared__ float prev[256];
  constexpr int LB[8] = {0,4,8,12,15,19,23,27};
  constexpr int NS[8] = {4,4,4,3,4,4,4,4};
  constexpr int CSV[8] = {1,1,1,1,2,1,2,1};
  const int s = blockIdx.x, n = threadIdx.x;
  float v;
  if (CSV[s] == 2) v = b3[(s == 4 ? 0 : 1) * 256 + n];
  else             v = b2[w2idx(LB[s]) * 256 + n];
  beff[(s * 4 + 0) * 256 + n] = v;
  prev[n] = v;
  __syncthreads();
  for (int d = 2; d <= NS[s]; ++d) {
    const int lw = w2idx(LB[s] + d - 1);
    const float* wr = w2 + ((long)(lw * 256 + n)) * 512;
    float acc = b2[lw * 256 + n];
#pragma unroll 8
    for (int c = 0; c < 256; c += 2) {
      fvec4 vv = *reinterpret_cast<const fvec4*>(wr + 2 * c);
      acc += (vv[0] + vv[1]) * prev[c] + (vv[2] + vv[3]) * prev[c + 1];
    }
    __syncthreads();
    prev[n] = acc;
    beff[(s * 4 + d - 1) * 256 + n] = acc;
    __syncthreads();
  }
}

// ---- compose body: Q[n,i,SH*a+tp] += wl[n,c,a] * P[c,i,tp] via MFMA (D[i][n]) ----
template<int WP, int SH>
__device__ __forceinline__ void compose_body(
    unsigned short* __restrict__ ws, long asrc, long bsrc, long qb, long qa,
    int tid, int bx)
{
  constexpr int TQ = WP + SH;
  const int iblk = bx & 7, nblk = bx >> 3;
  const int wave = tid >> 6, lane = tid & 63, l15 = lane & 15, quad = lane >> 4;
  const int nn = nblk * 64 + wave * 16 + l15;
  floatx4 acc[TQ][2];
#pragma unroll
  for (int q2 = 0; q2 < TQ; ++q2) {
    acc[q2][0] = (floatx4){0.f,0.f,0.f,0.f};
    acc[q2][1] = (floatx4){0.f,0.f,0.f,0.f};
  }
#pragma unroll
  for (int a = 0; a < 2; ++a) {
    const unsigned short* bp = ws + bsrc + a * 65536 + nn * 256 + quad * 8;
#pragma unroll
    for (int tp = 0; tp < WP; ++tp) {
      const int tau = SH * a + tp;
      const unsigned short* ap = ws + asrc + tp * 65536 + (iblk * 32 + l15) * 256 + quad * 8;
#pragma unroll
      for (int kc = 0; kc < 8; ++kc) {
        bf16x8 bf = *reinterpret_cast<const bf16x8*>(bp + kc * 32);
        bf16x8 a0 = *reinterpret_cast<const bf16x8*>(ap + kc * 32);
        bf16x8 a1 = *reinterpret_cast<const bf16x8*>(ap + 16 * 256 + kc * 32);
        acc[tau][0] = __builtin_amdgcn_mfma_f32_16x16x32_bf16(a0, bf, acc[tau][0], 0, 0, 0);
        acc[tau][1] = __builtin_amdgcn_mfma_f32_16x16x32_bf16(a1, bf, acc[tau][1], 0, 0, 0);
      }
    }
  }
#pragma unroll
  for (int tau = 0; tau < TQ; ++tau)
#pragma unroll
    for (int t = 0; t < 2; ++t) {
      const int i0 = iblk * 32 + t * 16 + quad * 4;
      ushort4v pk;
#pragma unroll
      for (int r = 0; r < 4; ++r) pk[r] = f2bf(acc[tau][t][r]);
      *reinterpret_cast<ushort4v*>(ws + qb + tau * 65536 + nn * 256 + i0) = pk;
      if (qa >= 0) {
#pragma unroll
        for (int r = 0; r < 4; ++r)
          ws[qa + (long)tau * 65536 + (long)(i0 + r) * 256 + nn] = pk[r];
      }
    }
}

template<int Q>
__global__ __launch_bounds__(256) void compose_kernel(unsigned short* __restrict__ ws)
{
  constexpr int CPAO[8] = {20971520,21430272,21889024,22347776,22544384,23330816,23789568,24576000};
  constexpr int CSV[8]  = {1,1,1,1,2,1,2,1};
  constexpr long A2SRC[8] = {3801088,4325376,4849664,5373952,7602176,6160384,7798784,7077888};
  constexpr int LW2[8] = {1,5,9,13,15,19,22,26};
  constexpr int LW3[8] = {2,6,10,14,16,20,23,27};
  constexpr int LW4[7] = {3,7,11,17,21,24,28};
  constexpr int S4[7]  = {0,1,2,4,5,6,7};
  const int j = blockIdx.y;
  const int s = (Q == 4) ? S4[j] : j;
  const int cs = CSV[s];
  long asrc, qa; int lw;
  if (Q == 2)      { asrc = A2SRC[j]; lw = LW2[j]; qa = CPAO[s]; }
  else if (Q == 3) { asrc = CPAO[s];  lw = LW3[j];
                     qa = (s == 3) ? -1 : CPAO[s] + (long)(cs == 1 ? 3 : 5) * 65536; }
  else             { asrc = CPAO[s] + (long)(cs == 1 ? 3 : 5) * 65536; lw = LW4[j]; qa = -1; }
  const long qb = (long)swo_at(s) +
      (long)(cs == 1 ? (Q == 2 ? 2 : Q == 3 ? 5 : 9)
                     : (Q == 2 ? 3 : Q == 3 ? 8 : 15)) * 65536;
  const long bsrc = (long)lw * 131072;
  const int tid = threadIdx.x, bx = blockIdx.x;
  if (cs == 1) {
    if (Q == 2)      compose_body<2, 1>(ws, asrc, bsrc, qb, qa, tid, bx);
    else if (Q == 3) compose_body<3, 1>(ws, asrc, bsrc, qb, qa, tid, bx);
    else             compose_body<4, 1>(ws, asrc, bsrc, qb, qa, tid, bx);
  } else {
    if (Q == 2)      compose_body<3, 2>(ws, asrc, bsrc, qb, qa, tid, bx);
    else if (Q == 3) compose_body<5, 2>(ws, asrc, bsrc, qb, qa, tid, bx);
    else             compose_body<7, 2>(ws, asrc, bsrc, qb, qa, tid, bx);
  }
}

// ---- stage sub-conv: W taps from the shared swizzled plane, tap-major B ----
template<int W, int CS, bool WRX>
__device__ __forceinline__ void sub_body(
    const unsigned short* __restrict__ PL,
    const unsigned short* __restrict__ Wsub, const float* __restrict__ bsub,
    float* __restrict__ Ysub, unsigned short* __restrict__ Xout, int Lpout,
    int Lout, int b, int m0, int nn, int l15, int quad)
{
  floatx4 acc0 = {0.f,0.f,0.f,0.f}, acc1 = {0.f,0.f,0.f,0.f};
  const unsigned short* wr = Wsub + nn * 256 + quad * 8;
#pragma unroll
  for (int t = 0; t < W; ++t) {
    const int r0 = CS * l15 + t, r1 = CS * (16 + l15) + t;
    const int b0 = r0 * 256, x0 = r0 & 7, b1 = r1 * 256, x1 = r1 & 7;
#pragma unroll
    for (int kc = 0; kc < 8; ++kc) {
      bf16x8 bf = *reinterpret_cast<const bf16x8*>(wr + t * 65536 + kc * 32);
      const int c8 = kc * 4 + quad;
      bf16x8 a0 = *reinterpret_cast<const bf16x8*>(&PL[b0 + ((c8 ^ x0) << 3)]);
      bf16x8 a1 = *reinterpret_cast<const bf16x8*>(&PL[b1 + ((c8 ^ x1) << 3)]);
      acc0 = __builtin_amdgcn_mfma_f32_16x16x32_bf16(a0, bf, acc0, 0, 0, 0);
      acc1 = __builtin_amdgcn_mfma_f32_16x16x32_bf16(a1, bf, acc1, 0, 0, 0);
    }
  }
  const float bv = bsub[nn];
  const int row = b * 256 + nn;
  float* yo = Ysub + (long)row * 128;
#pragma unroll
  for (int r = 0; r < 4; ++r) {
    const int m = m0 + quad * 4 + r;
    if (m < Lout) {
      const float v = acc0[r] + bv; yo[m] = v;
      if constexpr (WRX) Xout[(long)row * Lpout + m] = f2bf(v);
    }
    const int m2 = m0 + 16 + quad * 4 + r;
    if (m2 < Lout) {
      const float v = acc1[r] + bv; yo[m2] = v;
      if constexpr (WRX) Xout[(long)row * Lpout + m2] = f2bf(v);
    }
  }
}

// ---- fused stage: one LDS position-plane (swizzled) serves all subs/taps ----
template<int NSUB, int CS, bool XOUT>
__global__ __launch_bounds__(256) void stage_kernel(
    const unsigned short* __restrict__ Xin, unsigned short* __restrict__ Xout,
    const unsigned short* __restrict__ Wst, const float* __restrict__ bst,
    float* __restrict__ Ybase, int Lpin, int Lpout, int Lout1)
{
  constexpr int ROWS = (CS == 1) ? 36 : 72;
  constexpr int NV   = (CS == 1) ? 5 : 9;
  __shared__ unsigned short PL[ROWS * 256];
  const int tid = threadIdx.x, b = blockIdx.z, m0 = blockIdx.x * 32;
  {
    const int i = tid;
    const unsigned short* rp = Xin + ((long)(b * 256 + i) * Lpin) + CS * m0;
    ushort8v xr[NV];
#pragma unroll
    for (int v = 0; v < NV; ++v) xr[v] = *reinterpret_cast<const ushort8v*>(rp + v * 8);
    const unsigned short* xs = reinterpret_cast<const unsigned short*>(xr);
#pragma unroll
    for (int r = 0; r < ROWS; ++r)
      PL[r * 256 + ((((i >> 3) ^ (r & 7)) << 3) | (i & 7))] = xs[r];
  }
  __syncthreads();
  const int wave = tid >> 6, lane = tid & 63, l15 = lane & 15, quad = lane >> 4;
  const int nn = blockIdx.y * 64 + wave * 16 + l15;
  if (CS == 1) {
    sub_body<2,1,false>(PL, Wst,             bst,       Ybase,              Xout, Lpout, Lout1,     b, m0, nn, l15, quad);
    sub_body<3,1,false>(PL, Wst + 2*65536,   bst + 256, Ybase + 524288,     Xout, Lpout, Lout1 - 1, b, m0, nn, l15, quad);
    sub_body<4,1,(NSUB==3)&&XOUT>(PL, Wst + 5*65536, bst + 512, Ybase + 2*524288, Xout, Lpout, Lout1 - 2, b, m0, nn, l15, quad);
    if (NSUB == 4)
      sub_body<5,1,XOUT>(PL, Wst + 9*65536,  bst + 768, Ybase + 3*524288,   Xout, Lpout, Lout1 - 3, b, m0, nn, l15, quad);
  } else {
    sub_body<3,2,false>(PL, Wst,             bst,       Ybase,              Xout, Lpout, Lout1,     b, m0, nn, l15, quad);
    sub_body<5,2,false>(PL, Wst + 3*65536,   bst + 256, Ybase + 524288,     Xout, Lpout, Lout1 - 1, b, m0, nn, l15, quad);
    sub_body<7,2,false>(PL, Wst + 8*65536,   bst + 512, Ybase + 2*524288,   Xout, Lpout, Lout1 - 2, b, m0, nn, l15, quad);
    sub_body<9,2,XOUT>(PL, Wst + 15*65536,   bst + 768, Ybase + 3*524288,   Xout, Lpout, Lout1 - 3, b, m0, nn, l15, quad);
  }
}

// ---- assemble (unchanged, proven) ----
__global__ __launch_bounds__(256) void assemble_kernel(
    float* __restrict__ out, const float* __restrict__ x,
    const unsigned short* __restrict__ tbl, const float* __restrict__ Y)
{
  __shared__ float S[32 * 129];
  const int blk = blockIdx.x;
  const int tid = threadIdx.x;
  {
    const int m = tid & 127, half = tid >> 7;
#pragma unroll
    for (int lp = 0; lp < 16; ++lp) {
      const int l = lp * 2 + half;
      if (l < 31) {
        const int Lout = (l < 15) ? (127 - l)
                       : (l == 15) ? 56
                       : (l < 23)  ? (71 - l)
                       : (l == 23) ? 24 : (47 - l);
        if (m < Lout) S[l * 129 + m] = Y[(long)l * 524288 + blk * 128 + m];
      } else {
        S[31 * 129 + m] = x[blk * 128 + m];
      }
    }
  }
  __syncthreads();
  const long obase = (long)blk << 14;
#pragma unroll 1
  for (int it = 0; it < 16; ++it) {
    const int flat = it * 256 + tid;
    ushort4v t4 = *reinterpret_cast<const ushort4v*>(tbl + 4 * flat);
    fvec4 v;
#pragma unroll
    for (int jj = 0; jj < 4; ++jj) {
      const unsigned short t = t4[jj];
      const int idx = (t == 0xFFFFu) ? 0 : (int)t;
      const float sv = S[idx];
      v[jj] = (t == 0xFFFFu) ? 0.f : sv;
    }
    *reinterpret_cast<fvec4*>(out + obase + 4 * flat) = v;
  }
}

extern "C" void kernel_launch(void* const* d_in, const int* in_sizes, int n_in,
                              void* d_out, int out_size, void* d_ws, size_t ws_size,
                              hipStream_t stream)
{
  const float* x  = (const float*)d_in[0];
  const float* w2 = (const float*)d_in[1];
  const float* b2 = (const float*)d_in[2];
  const float* w3 = (const float*)d_in[3];
  const float* b3 = (const float*)d_in[4];
  float* out = (float*)d_out;
  unsigned short* ws = (unsigned short*)d_ws;
  float* beff = (float*)((char*)d_ws + BEFF_B);
  float* Y = (float*)((char*)d_ws + Y_B);

  prep0_kernel<<<5184, 256, 0, stream>>>(w2, w3, x, ws);
  wt_kernel<<<496, 256, 0, stream>>>(w2, w3, ws);
  beff_kernel<<<8, 256, 0, stream>>>(w2, b2, b3, beff);
  compose_kernel<2><<<dim3(32, 8), 256, 0, stream>>>(ws);
  compose_kernel<3><<<dim3(32, 8), 256, 0, stream>>>(ws);
  compose_kernel<4><<<dim3(32, 7), 256, 0, stream>>>(ws);

  // A1: layers 0-3, in X0(p136) -> X4(p136)
  stage_kernel<4,1,true><<<dim3(4,4,16), 256, 0, stream>>>(
      ws + X0_E, ws + X4_E, ws + swo_at(0), beff + 0*1024, Y, 136, 136, 127);
  // A2: layers 4-7
  stage_kernel<4,1,true><<<dim3(4,4,16), 256, 0, stream>>>(
      ws + X4_E, ws + X8_E, ws + swo_at(1), beff + 1*1024, Y + (long)4*524288, 136, 136, 123);
  // A3: layers 8-11
  stage_kernel<4,1,true><<<dim3(4,4,16), 256, 0, stream>>>(
      ws + X8_E, ws + X12_E, ws + swo_at(2), beff + 2*1024, Y + (long)8*524288, 136, 136, 119);
  // A4: layers 12-14 (3 subs)
  stage_kernel<3,1,true><<<dim3(4,4,16), 256, 0, stream>>>(
      ws + X12_E, ws + X15_E, ws + swo_at(3), beff + 3*1024, Y + (long)12*524288, 136, 136, 115);
  // B1: layers 15-18 (k3/k5/k7/k9 s2), X15(p136) -> X19(p72)
  stage_kernel<4,2,true><<<dim3(2,4,16), 256, 0, stream>>>(
      ws + X15_E, ws + X19_E, ws + swo_at(4), beff + 4*1024, Y + (long)15*524288, 136, 72, 56);
  // B2: layers 19-22, X19(p72) -> X23(p72)
  stage_kernel<4,1,true><<<dim3(2,4,16), 256, 0, stream>>>(
      ws + X19_E, ws + X23_E, ws + swo_at(5), beff + 5*1024, Y + (long)19*524288, 72, 72, 52);
  // C1: layers 23-26 (s2), X23(p72) -> X27(p40)
  stage_kernel<4,2,true><<<dim3(1,4,16), 256, 0, stream>>>(
      ws + X23_E, ws + X27_E, ws + swo_at(6), beff + 6*1024, Y + (long)23*524288, 72, 40, 24);
  // C2: layers 27-30, no carrier
  stage_kernel<4,1,false><<<dim3(1,4,16), 256, 0, stream>>>(
      ws + X27_E, (unsigned short*)0, ws + swo_at(7), beff + 7*1024, Y + (long)27*524288, 40, 0, 20);

  assemble_kernel<<<4096, 256, 0, stream>>>(out, x, ws + TBL_E, Y);
}

// Round 7
// 562.348 us; speedup vs baseline: 1.1229x; 1.1229x over previous
//
#include <hip/hip_runtime.h>

// ---- types ----
typedef __bf16 bf16x8 __attribute__((ext_vector_type(8)));
typedef float  floatx4 __attribute__((ext_vector_type(4)));
typedef float  fvec4  __attribute__((ext_vector_type(4)));
typedef unsigned short ushort4v __attribute__((ext_vector_type(4)));
typedef unsigned short ushort8v __attribute__((ext_vector_type(8)));

__device__ __forceinline__ unsigned short f2bf(float f) {
  unsigned int u = __float_as_uint(f);
  u = u + 0x7FFFu + ((u >> 16) & 1u);   // RNE
  return (unsigned short)(u >> 16);
}

// ws layout (byte offsets):
//   0        : WP2 bf16  (29 * 256 * 512)
//   7602176  : WP3 bf16  (2 * 256 * 768)
//   8388608  : X0 bf16 (16*256*128), then pitched per-layer bf16 activations
//   32 MiB   : tbl u16 [2][64][128]  (per-half assemble index table)
//   64 MiB   : Y fp32 [31][16*256][128]
#define WP3_OFF   3801088    // ushort elems
#define X0_OFF    4194304    // ushort elems
#define TBL_E     16777216   // ushort elems (byte 32 MiB)
#define Y_OFF_B   (64u << 20)

// ---- prep: fp32 -> bf16 copies (w2, w3, x0). Layout [o][i][k] == MFMA-B row order.
__global__ __launch_bounds__(256) void prep_kernel(
    const float* __restrict__ w2, const float* __restrict__ w3,
    const float* __restrict__ x, unsigned short* __restrict__ ws)
{
  int g = blockIdx.x * 256 + threadIdx.x;
  const float* src; unsigned short* dst;
  if (g < 950272)            { src = w2; dst = ws; }
  else if (g < 950272+98304) { g -= 950272; src = w3; dst = ws + WP3_OFF; }
  else                       { g -= (950272+98304); src = x; dst = ws + X0_OFF; }
  fvec4 v = *reinterpret_cast<const fvec4*>(src + 4*g);
  ushort4v o;
  o[0] = f2bf(v[0]); o[1] = f2bf(v[1]); o[2] = f2bf(v[2]); o[3] = f2bf(v[3]);
  *reinterpret_cast<ushort4v*>(dst + 4*g) = o;
}

// ---- per-half index table: entry (h, rl, c) -> S-index (slot*65 + local m),
// diag slot 31, or 0xFFFF. Validity as proved offline (m<Lout follows from c<128).
__global__ __launch_bounds__(256) void tbl_kernel(unsigned short* __restrict__ tbl)
{
  const int g = blockIdx.x * 256 + threadIdx.x;   // 0..16383
  const int h = g >> 13, rl = (g >> 7) & 63, c = g & 127;
  const int r = h * 64 + rl, d = c - r;
  unsigned short v = 0xFFFFu;
  if (d == 0) v = (unsigned short)(31 * 65 + rl);
  else if (d >= 1 && d <= 15) v = (unsigned short)((d - 1) * 65 + rl);
  else if (d >= 17 && d <= 31 && (d & 1) == 1 && (r & 1) == 0)
    v = (unsigned short)((15 + ((d - 17) >> 1)) * 65 + (rl >> 1));
  else if (d >= 35 && d <= 63 && (d & 3) == 3 && (r & 3) == 0)
    v = (unsigned short)((23 + ((d - 35) >> 2)) * 65 + (rl >> 2));
  tbl[g] = v;
}

// ---- conv layer (R2 structure, m-tile 16 => 512 blocks = 2/CU for big layers).
// Y[b,n,m] = sum_{i,k} W[n,i,k]*X[b,i,cs*m+k] + bias[n]. Bit-identical K-order to R2.
template<int KW>
__global__ __launch_bounds__(256) void conv_kernel(
    const unsigned short* __restrict__ Xin,   // [16*256][Lpin] bf16
    unsigned short* __restrict__ Xout,        // [16*256][Lpout] bf16
    const unsigned short* __restrict__ WP,    // [256][KS] bf16
    const float* __restrict__ bias,           // [256]
    float* __restrict__ Yl,                   // [16*256][128] fp32 compact
    int Lpin, int Lout, int Lpout)
{
  constexpr int CS    = (KW == 3) ? 2 : 1;
  constexpr int KS    = 256 * KW;
  constexpr int pitch = KS + 8;
  constexpr int SPAN  = CS * 15 + KW;        // 17 (k2) / 33 (k3)
  constexpr int NV    = (SPAN + 7) / 8;      // 3 / 5
  __shared__ unsigned short LA[16 * pitch];

  const int tid = threadIdx.x;
  const int b   = blockIdx.z;
  const int m0  = blockIdx.x * 16;
  const int n0  = blockIdx.y * 64;

  // ---- stage A tile (vectorized row loads; tail garbage only feeds m>=Lout) ----
  {
    const int i = tid;
    const unsigned short* rp = Xin + ((b * 256 + i) * Lpin) + CS * m0;
    ushort8v xr[NV];
#pragma unroll
    for (int v = 0; v < NV; ++v)
      xr[v] = *reinterpret_cast<const ushort8v*>(rp + v * 8);
    const unsigned short* xs = reinterpret_cast<const unsigned short*>(xr);
    if (KW == 2) {
#pragma unroll
      for (int m = 0; m < 16; ++m) {
        unsigned int pk = (unsigned int)xs[m] | ((unsigned int)xs[m + 1] << 16);
        *reinterpret_cast<unsigned int*>(&LA[m * pitch + 2 * i]) = pk;
      }
    } else {
#pragma unroll
      for (int m = 0; m < 16; ++m) {
        int base = m * pitch + 3 * i;
        LA[base]     = xs[2 * m];
        LA[base + 1] = xs[2 * m + 1];
        LA[base + 2] = xs[2 * m + 2];
      }
    }
  }
  __syncthreads();

  const int wave = tid >> 6, lane = tid & 63;
  const int l15 = lane & 15, quad = lane >> 4;
  const int nn = n0 + wave * 16 + l15;
  const float bv = bias[nn];
  const unsigned short* wrow = WP + (long)nn * KS + quad * 8;

  floatx4 acc = {0.f, 0.f, 0.f, 0.f};
  constexpr int niter = KS / 32;
#pragma unroll
  for (int kc = 0; kc < niter; ++kc) {
    bf16x8 bfrag = *reinterpret_cast<const bf16x8*>(wrow + kc * 32);
    bf16x8 a = *reinterpret_cast<const bf16x8*>(&LA[l15 * pitch + quad * 8 + kc * 32]);
    acc = __builtin_amdgcn_mfma_f32_16x16x32_bf16(a, bfrag, acc, 0, 0, 0);
  }

  const int row = b * 256 + nn;
  unsigned short* xo = Xout + (long)row * Lpout;
  float* yo = Yl + (long)row * 128;
#pragma unroll
  for (int r = 0; r < 4; ++r) {
    const int m = m0 + quad * 4 + r;
    if (m < Lout) {
      const float v = acc[r] + bv;
      xo[m] = f2bf(v);
      yo[m] = v;
    }
  }
}

// ---- assemble v4: one block per (b,ch,row-half). 8.3KB LDS stage (pitch 65),
// tbl loads hoisted before the store loop; writes 32KB coalesced per block.
__global__ __launch_bounds__(256) void assemble_kernel(
    float* __restrict__ out, const float* __restrict__ x,
    const unsigned short* __restrict__ tbl, const float* __restrict__ Y)
{
  __shared__ float S[32 * 65];
  const int bh = blockIdx.x;          // 0..8191
  const int blk = bh >> 1, h = bh & 1;
  const int tid = threadIdx.x;

  // hoist the 8 table vec-reads (L2-hot, same for every blk of this half)
  ushort4v t4s[8];
  const unsigned short* tb = tbl + h * 8192;
#pragma unroll
  for (int it = 0; it < 8; ++it)
    t4s[it] = *reinterpret_cast<const ushort4v*>(tb + 4 * (it * 256 + tid));

  // stage this half's windows: s1 layers need 64, s2 need 32, s4 need 16, diag 64
#pragma unroll
  for (int p = 0; p < 8; ++p) {
    const int idx = p * 256 + tid;    // 0..2047 over [32 slots][64]
    const int slot = idx >> 6, m = idx & 63;
    if (slot < 15) {
      const int mm = h * 64 + m;
      if (mm < 127 - slot) S[slot * 65 + m] = Y[(long)slot * 524288 + blk * 128 + mm];
    } else if (slot < 23) {
      if (m < 32) {
        const int mm = h * 32 + m;
        const int Lout = (slot == 15) ? 56 : (71 - slot);
        if (mm < Lout) S[slot * 65 + m] = Y[(long)slot * 524288 + blk * 128 + mm];
      }
    } else if (slot < 31) {
      if (m < 16) {
        const int mm = h * 16 + m;
        const int Lout = (slot == 23) ? 24 : (47 - slot);
        if (mm < Lout) S[slot * 65 + m] = Y[(long)slot * 524288 + blk * 128 + mm];
      }
    } else {
      S[31 * 65 + m] = x[blk * 128 + h * 64 + m];
    }
  }
  __syncthreads();

  const long obase = ((long)blk << 14) + ((long)h << 13);
#pragma unroll
  for (int it = 0; it < 8; ++it) {
    const int flat = it * 256 + tid;
    const ushort4v t4 = t4s[it];
    fvec4 v;
#pragma unroll
    for (int jj = 0; jj < 4; ++jj) {
      const unsigned short t = t4[jj];
      const int idx = (t == 0xFFFFu) ? 0 : (int)t;
      const float sv = S[idx];
      v[jj] = (t == 0xFFFFu) ? 0.f : sv;
    }
    *reinterpret_cast<fvec4*>(out + obase + 4 * flat) = v;
  }
}

extern "C" void kernel_launch(void* const* d_in, const int* in_sizes, int n_in,
                              void* d_out, int out_size, void* d_ws, size_t ws_size,
                              hipStream_t stream)
{
  const float* x  = (const float*)d_in[0];
  const float* w2 = (const float*)d_in[1];
  const float* b2 = (const float*)d_in[2];
  const float* w3 = (const float*)d_in[3];
  const float* b3 = (const float*)d_in[4];
  float* out = (float*)d_out;
  unsigned short* ws = (unsigned short*)d_ws;
  unsigned short* tbl = ws + TBL_E;
  float* Y = (float*)((char*)d_ws + Y_OFF_B);

  prep_kernel<<<4608, 256, 0, stream>>>(w2, w3, x, ws);
  tbl_kernel<<<64, 256, 0, stream>>>(tbl);

  const int counts[3] = {15, 8, 8};
  int stride = 1, offset = 0;
  int Lin = 128, Lpin = 128;
  int c2 = 0, c3 = 0, lidx = 0;
  long xprev = X0_OFF;
  long xnext = xprev + (long)16 * 256 * 128 + 64;
  for (int ci = 0; ci < 3; ++ci) {
    for (int k = 0; k < counts[ci]; ++k) {
      offset += stride;
      int KW = (ci > 0 && k == 0) ? 3 : 2;
      int cs = (KW == 3) ? 2 : 1;
      int Lout = (Lin - KW) / cs + 1;
      int Lpout = (Lout + 7) & ~7;
      const unsigned short* WPt; const float* bt;
      if (KW == 2) { WPt = ws + (long)c2 * 131072; bt = b2 + c2 * 256; ++c2; }
      else         { WPt = ws + WP3_OFF + (long)c3 * 196608; bt = b3 + c3 * 256; ++c3; }
      dim3 grid((Lout + 15) / 16, 4, 16);
      if (KW == 2)
        conv_kernel<2><<<grid, 256, 0, stream>>>(
            ws + xprev, ws + xnext, WPt, bt, Y + (long)lidx * 524288,
            Lpin, Lout, Lpout);
      else
        conv_kernel<3><<<grid, 256, 0, stream>>>(
            ws + xprev, ws + xnext, WPt, bt, Y + (long)lidx * 524288,
            Lpin, Lout, Lpout);
      ++lidx;
      xprev = xnext;
      xnext += (long)16 * 256 * Lpout + 64;
      Lin = Lout; Lpin = Lpout;
    }
    stride *= 2;
  }

  assemble_kernel<<<8192, 256, 0, stream>>>(out, x, tbl, Y);
}

// Round 8
// 523.667 us; speedup vs baseline: 1.2059x; 1.0739x over previous
//
#include <hip/hip_runtime.h>

// ---- types ----
typedef __bf16 bf16x8 __attribute__((ext_vector_type(8)));
typedef float  floatx4 __attribute__((ext_vector_type(4)));
typedef float  fvec4  __attribute__((ext_vector_type(4)));
typedef unsigned short ushort4v __attribute__((ext_vector_type(4)));

__device__ __forceinline__ unsigned short f2bf(float f) {
  unsigned int u = __float_as_uint(f);
  u = u + 0x7FFFu + ((u >> 16) & 1u);   // RNE
  return (unsigned short)(u >> 16);
}

// async 16B global->LDS (m97 pattern: literal size 16, wave-uniform LDS base,
// per-lane global address).
__device__ __forceinline__ void gload_lds16(const unsigned short* g, unsigned short* l) {
  __builtin_amdgcn_global_load_lds(
      (const __attribute__((address_space(1))) unsigned int*)(g),
      (__attribute__((address_space(3))) unsigned int*)(l), 16, 0, 0);
}

// ws layout (u16-elem offsets unless noted):
//   0        : WP2 bf16 [29][256][512]
//   3801088  : WP3 bf16 [2][256][768]
//   8388608  : carriers: per-layer k-major swizzled activations.
//              carrier[l]: [16 b][ROWS][WROW] u16, WROW=512 (KW2, 128 rows)
//              or 768 (KW3, 64 rows). elem (m,c) stored at m*WROW + (c ^ ((m&7)<<3)).
//   90 MiB   : tbl u16 [2][64][128] (assemble)
//   96 MiB   : Y fp32 [31][16*256][128]
#define WP3_OFF   3801088
#define XC0_E     8388608
#define TBL_E     47185920
#define Y_B       100663296

// ---- prep: bf16 weight copies + X0 carrier (k-major swizzled) ----
__global__ __launch_bounds__(256) void prep_kernel(
    const float* __restrict__ w2, const float* __restrict__ w3,
    const float* __restrict__ x, unsigned short* __restrict__ ws)
{
  int g = blockIdx.x * 256 + threadIdx.x;          // 0 .. 1179647
  if (g < 1048576) {
    const float* src; unsigned short* dst;
    if (g < 950272) { src = w2; dst = ws; }
    else            { g -= 950272; src = w3; dst = ws + WP3_OFF; }
    fvec4 v = *reinterpret_cast<const fvec4*>(src + 4 * g);
    ushort4v o;
    o[0] = f2bf(v[0]); o[1] = f2bf(v[1]); o[2] = f2bf(v[2]); o[3] = f2bf(v[3]);
    *reinterpret_cast<ushort4v*>(dst + 4 * g) = o;
  } else {
    const int h = g - 1048576;                     // 0..131071 over x float4 groups
    const long f = (long)4 * h;
    const int bb = (int)(f >> 15);
    const int i  = (int)((f >> 7) & 255);
    const int p0 = (int)(f & 127);
    fvec4 v = *reinterpret_cast<const fvec4*>(x + f);
    unsigned short* xb = ws + XC0_E + (long)bb * 65536;
#pragma unroll
    for (int j = 0; j < 4; ++j) {
      const int p = p0 + j;
      const unsigned short bf = f2bf(v[j]);
      xb[p * 512 + ((2 * i) ^ ((p & 7) << 3))] = bf;
      if (p >= 1) xb[(p - 1) * 512 + ((2 * i + 1) ^ (((p - 1) & 7) << 3))] = bf;
    }
  }
}

// ---- per-half assemble index table (validated in R7) ----
__global__ __launch_bounds__(256) void tbl_kernel(unsigned short* __restrict__ tbl)
{
  const int g = blockIdx.x * 256 + threadIdx.x;   // 0..16383
  const int h = g >> 13, rl = (g >> 7) & 63, c = g & 127;
  const int r = h * 64 + rl, d = c - r;
  unsigned short v = 0xFFFFu;
  if (d == 0) v = (unsigned short)(31 * 65 + rl);
  else if (d >= 1 && d <= 15) v = (unsigned short)((d - 1) * 65 + rl);
  else if (d >= 17 && d <= 31 && (d & 1) == 1 && (r & 1) == 0)
    v = (unsigned short)((15 + ((d - 17) >> 1)) * 65 + (rl >> 1));
  else if (d >= 35 && d <= 63 && (d & 3) == 3 && (r & 3) == 0)
    v = (unsigned short)((23 + ((d - 35) >> 2)) * 65 + (rl >> 2));
  tbl[g] = v;
}

// ---- conv layer: R2 geometry (MT=32, dual acc), k-major swizzled carriers,
// async global_load_lds staging (flat coalesced copy, linear LDS).
// Bit-identical K-order to R2.
template<int KW, int KWN>
__global__ __launch_bounds__(256) void conv_kernel(
    const unsigned short* __restrict__ Xin,   // carrier[l]
    unsigned short* __restrict__ Xout,        // carrier[l+1] (KWN!=0)
    const unsigned short* __restrict__ WP,    // [256][KS] bf16
    const float* __restrict__ bias,           // [256]
    float* __restrict__ Yl,                   // [16*256][128] fp32 compact
    int Lout)
{
  constexpr int WROW  = 256 * KW;                 // u16 per carrier row
  constexpr int BSTR  = (KW == 2) ? 65536 : 49152;
  constexpr int BSTRN = (KWN == 3) ? 49152 : 65536;
  constexpr int KS    = 256 * KW;
  constexpr int NLD   = (KW == 2) ? 8 : 12;       // gload16 per wave (1KB each)
  __shared__ unsigned short LA[32 * WROW];

  const int tid = threadIdx.x, wave = tid >> 6, lane = tid & 63;
  const int b = blockIdx.z, m0 = blockIdx.x * 32, n0 = blockIdx.y * 64;

  // ---- async stage: rows m0..m0+31 are one contiguous swizzled block ----
  {
    const unsigned short* src = Xin + (long)b * BSTR + (long)m0 * WROW
                              + wave * (NLD * 512) + lane * 8;
    unsigned short* dst = &LA[wave * (NLD * 512)];
#pragma unroll
    for (int v = 0; v < NLD; ++v)
      gload_lds16(src + v * 512, dst + v * 512);
  }
  __syncthreads();   // drains vmcnt(0): all waves' loads complete

  const int l15 = lane & 15, quad = lane >> 4;
  const int nn = n0 + wave * 16 + l15;
  const float bv = bias[nn];
  const unsigned short* wrow = WP + (long)nn * KS + quad * 8;
  const int sx = (l15 & 7) << 3;                  // 16B-granule XOR (u16 units)

  floatx4 acc0 = {0.f, 0.f, 0.f, 0.f};
  floatx4 acc1 = {0.f, 0.f, 0.f, 0.f};
#pragma unroll
  for (int kc = 0; kc < KS / 32; ++kc) {
    bf16x8 bfrag = *reinterpret_cast<const bf16x8*>(wrow + kc * 32);
    const int ko = (quad * 8 + kc * 32) ^ sx;
    bf16x8 a0 = *reinterpret_cast<const bf16x8*>(&LA[l15 * WROW + ko]);
    bf16x8 a1 = *reinterpret_cast<const bf16x8*>(&LA[(16 + l15) * WROW + ko]);
    acc0 = __builtin_amdgcn_mfma_f32_16x16x32_bf16(a0, bfrag, acc0, 0, 0, 0);
    acc1 = __builtin_amdgcn_mfma_f32_16x16x32_bf16(a1, bfrag, acc1, 0, 0, 0);
  }

  const int row = b * 256 + nn;
  float* yo = Yl + (long)row * 128;
  unsigned short* xb = (KWN != 0) ? (Xout + (long)b * BSTRN) : (unsigned short*)0;
#pragma unroll
  for (int half = 0; half < 2; ++half) {
    const floatx4& A = half ? acc1 : acc0;
#pragma unroll
    for (int r = 0; r < 4; ++r) {
      const int m = m0 + half * 16 + quad * 4 + r;
      if (m < Lout) {
        const float v = A[r] + bv;
        yo[m] = v;
        const unsigned short bf = f2bf(v);
        if constexpr (KWN == 2) {
          xb[m * 512 + ((2 * nn) ^ ((m & 7) << 3))] = bf;
          if (m >= 1) xb[(m - 1) * 512 + ((2 * nn + 1) ^ (((m - 1) & 7) << 3))] = bf;
        } else if constexpr (KWN == 3) {
          if ((m & 1) == 0) {
            const int mh = m >> 1;
            xb[mh * 768 + ((3 * nn) ^ ((mh & 7) << 3))] = bf;
            if (m >= 2) xb[(mh - 1) * 768 + ((3 * nn + 2) ^ (((mh - 1) & 7) << 3))] = bf;
          } else {
            const int mh = m >> 1;
            xb[mh * 768 + ((3 * nn + 1) ^ ((mh & 7) << 3))] = bf;
          }
        }
      }
    }
  }
}

// ---- assemble v4 (validated R7): per (b,ch,row-half); hoisted tbl; 8.3KB LDS ----
__global__ __launch_bounds__(256) void assemble_kernel(
    float* __restrict__ out, const float* __restrict__ x,
    const unsigned short* __restrict__ tbl, const float* __restrict__ Y)
{
  __shared__ float S[32 * 65];
  const int bh = blockIdx.x;          // 0..8191
  const int blk = bh >> 1, h = bh & 1;
  const int tid = threadIdx.x;

  ushort4v t4s[8];
  const unsigned short* tb = tbl + h * 8192;
#pragma unroll
  for (int it = 0; it < 8; ++it)
    t4s[it] = *reinterpret_cast<const ushort4v*>(tb + 4 * (it * 256 + tid));

#pragma unroll
  for (int p = 0; p < 8; ++p) {
    const int idx = p * 256 + tid;
    const int slot = idx >> 6, m = idx & 63;
    if (slot < 15) {
      const int mm = h * 64 + m;
      if (mm < 127 - slot) S[slot * 65 + m] = Y[(long)slot * 524288 + blk * 128 + mm];
    } else if (slot < 23) {
      if (m < 32) {
        const int mm = h * 32 + m;
        const int Lout = (slot == 15) ? 56 : (71 - slot);
        if (mm < Lout) S[slot * 65 + m] = Y[(long)slot * 524288 + blk * 128 + mm];
      }
    } else if (slot < 31) {
      if (m < 16) {
        const int mm = h * 16 + m;
        const int Lout = (slot == 23) ? 24 : (47 - slot);
        if (mm < Lout) S[slot * 65 + m] = Y[(long)slot * 524288 + blk * 128 + mm];
      }
    } else {
      S[31 * 65 + m] = x[blk * 128 + h * 64 + m];
    }
  }
  __syncthreads();

  const long obase = ((long)blk << 14) + ((long)h << 13);
#pragma unroll
  for (int it = 0; it < 8; ++it) {
    const int flat = it * 256 + tid;
    const ushort4v t4 = t4s[it];
    fvec4 v;
#pragma unroll
    for (int jj = 0; jj < 4; ++jj) {
      const unsigned short t = t4[jj];
      const int idx = (t == 0xFFFFu) ? 0 : (int)t;
      const float sv = S[idx];
      v[jj] = (t == 0xFFFFu) ? 0.f : sv;
    }
    *reinterpret_cast<fvec4*>(out + obase + 4 * flat) = v;
  }
}

extern "C" void kernel_launch(void* const* d_in, const int* in_sizes, int n_in,
                              void* d_out, int out_size, void* d_ws, size_t ws_size,
                              hipStream_t stream)
{
  const float* x  = (const float*)d_in[0];
  const float* w2 = (const float*)d_in[1];
  const float* b2 = (const float*)d_in[2];
  const float* w3 = (const float*)d_in[3];
  const float* b3 = (const float*)d_in[4];
  float* out = (float*)d_out;
  unsigned short* ws = (unsigned short*)d_ws;
  unsigned short* tbl = ws + TBL_E;
  float* Y = (float*)((char*)d_ws + Y_B);

  prep_kernel<<<4608, 256, 0, stream>>>(w2, w3, x, ws);
  tbl_kernel<<<64, 256, 0, stream>>>(tbl);

  long cin = XC0_E;                 // carrier[0]
  int Lin = 128;
  int c2 = 0, c3 = 0;
  for (int l = 0; l < 31; ++l) {
    const int KW = (l == 15 || l == 23) ? 3 : 2;
    const int cs = (KW == 3) ? 2 : 1;
    const int Lout = (Lin - KW) / cs + 1;
    const int KWN = (l == 30) ? 0 : ((l == 14 || l == 22) ? 3 : 2);
    const long cnext = cin + (long)16 * ((KW == 2) ? 65536 : 49152);
    const unsigned short* WPt; const float* bt;
    if (KW == 2) { WPt = ws + (long)c2 * 131072; bt = b2 + c2 * 256; ++c2; }
    else         { WPt = ws + WP3_OFF + (long)c3 * 196608; bt = b3 + c3 * 256; ++c3; }
    dim3 grid((Lout + 31) / 32, 4, 16);
    float* Yl = Y + (long)l * 524288;
    if (KW == 2 && KWN == 2)
      conv_kernel<2,2><<<grid, 256, 0, stream>>>(ws + cin, ws + cnext, WPt, bt, Yl, Lout);
    else if (KW == 2 && KWN == 3)
      conv_kernel<2,3><<<grid, 256, 0, stream>>>(ws + cin, ws + cnext, WPt, bt, Yl, Lout);
    else if (KW == 3 && KWN == 2)
      conv_kernel<3,2><<<grid, 256, 0, stream>>>(ws + cin, ws + cnext, WPt, bt, Yl, Lout);
    else
      conv_kernel<2,0><<<grid, 256, 0, stream>>>(ws + cin, (unsigned short*)0, WPt, bt, Yl, Lout);
    cin = cnext;
    Lin = Lout;
  }

  assemble_kernel<<<8192, 256, 0, stream>>>(out, x, tbl, Y);
}